// Round 8
// baseline (15446.608 us; speedup 1.0000x reference)
//
#include <hip/hip_runtime.h>
#include <math.h>

#define Nn 131072
#define Ee 524288
#define LROW 224              // limb-plane row stride (shorts): msg[0,100) pad[100,112) h[112,212) pad[212,224)

typedef __attribute__((ext_vector_type(8))) short short8;
typedef __attribute__((ext_vector_type(4))) float f32x4;
typedef unsigned short ushort_t;
typedef unsigned int uint32;

__device__ __forceinline__ f32x4 mfma16(short8 a, short8 b, f32x4 c) {
    return __builtin_amdgcn_mfma_f32_16x16x32_bf16(a, b, c, 0, 0, 0);
}

__device__ __forceinline__ uint32 rne_bf16(float x) {
    uint32 u = __float_as_uint(x);
    return (u + 0x7FFFu + ((u >> 16) & 1u)) >> 16;
}

// fp32 -> 3 bf16 limbs (hi, mid, lo). Lossless for normal fp32 (8+8+8 mantissa
// bits, Sterbenz-exact residuals); (l+m)+h reconstructs x exactly.
__device__ __forceinline__ void split3(float x, uint32& h, uint32& m, uint32& l) {
    h = rne_bf16(x);
    float hf = __uint_as_float(h << 16);
    float r1 = x - hf;
    m = rne_bf16(r1);
    float mf = __uint_as_float(m << 16);
    float r2 = r1 - mf;
    l = rne_bf16(r2);
}

__device__ __forceinline__ float limb2f(ushort_t u) {
    return __uint_as_float((uint32)u << 16);
}

// ---------------------------------------------------------------- diag / zero
__global__ void diag_kernel(float* out, float val) {
    int n = blockIdx.x * 256 + threadIdx.x;
    if (n < Nn) out[n] = (n == 0) ? val : 0.f;
}
__global__ void zero_ints(int* p, int n) {
    int i = blockIdx.x * 256 + threadIdx.x;
    if (i < n) p[i] = 0;
}
__global__ void zero_short8(ushort_t* p, long n8) {
    long i = (long)blockIdx.x * 256 + threadIdx.x;
    if (i < n8) {
        short8 zz = {0, 0, 0, 0, 0, 0, 0, 0};
        *(short8*)(p + i * 8) = zz;
    }
}

// ---------------------------------------------------------------- CSR build
__global__ void hist_kernel(const int* __restrict__ er, const int* __restrict__ ec,
                            int* __restrict__ cnt_f, int* __restrict__ cnt_b) {
    int e = blockIdx.x * 256 + threadIdx.x;
    atomicAdd(&cnt_f[er[e]], 1);
    atomicAdd(&cnt_b[ec[e]], 1);
}

// two independent scans in one launch; int4-vectorized serial phases
__global__ __launch_bounds__(1024) void scan2_kernel(
    const int* __restrict__ cnt_f, const int* __restrict__ cnt_b,
    int* __restrict__ ptr_f, int* __restrict__ ptr_b, int n) {
    const int* cnt = blockIdx.x ? cnt_b : cnt_f;
    int* ptr = blockIdx.x ? ptr_b : ptr_f;
    __shared__ int sums[1024];
    int t = threadIdx.x;
    int chunk = n >> 10;                 // 128
    int base = t * chunk;
    const int4* cp = (const int4*)(cnt + base);
    int s = 0;
#pragma unroll 4
    for (int i = 0; i < 32; i++) {
        int4 v = cp[i];
        s += v.x + v.y + v.z + v.w;
    }
    sums[t] = s;
    __syncthreads();
    for (int off = 1; off < 1024; off <<= 1) {
        int v = (t >= off) ? sums[t - off] : 0;
        __syncthreads();
        sums[t] += v;
        __syncthreads();
    }
    int run = (t == 0) ? 0 : sums[t - 1];
    int4* pp = (int4*)(ptr + base);
#pragma unroll 4
    for (int i = 0; i < 32; i++) {
        int4 v = cp[i];
        int4 o;
        o.x = run; run += v.x;
        o.y = run; run += v.y;
        o.z = run; run += v.z;
        o.w = run; run += v.w;
        pp[i] = o;
    }
    if (t == 1023) ptr[n] = run;
}

// fill advances ptr in place; afterwards start(r) = (r ? ptr[r-1] : 0), end(r) = ptr[r]
__global__ void fill_kernel(const int* __restrict__ er, const int* __restrict__ ec,
                            int* __restrict__ ptr_f, int* __restrict__ ptr_b,
                            int* __restrict__ src_f, int* __restrict__ src_b) {
    int e = blockIdx.x * 256 + threadIdx.x;
    int r = er[e], c = ec[e];
    int p = atomicAdd(&ptr_f[r], 1); src_f[p] = c;
    int q = atomicAdd(&ptr_b[c], 1); src_b[q] = r;
}

// ---------------------------------------------------------------- weight prep
// GRU: Wt[c=4d+g][k], c<448 (28 tiles), k<224.
// k<100: Wih[., k] (msg input), 112<=k<212: Whh[., k-112] (h input), else 0.
__global__ void prep_gru_w(const float* __restrict__ Wih, const float* __restrict__ Whh,
                           const float* __restrict__ bih, const float* __restrict__ bhh,
                           ushort_t* __restrict__ W0, ushort_t* __restrict__ W1,
                           ushort_t* __restrict__ W2, float* __restrict__ bg) {
    int gid = blockIdx.x * 256 + threadIdx.x;
    if (gid >= 448 * 224) return;
    int c = gid / 224, k = gid - c * 224;
    int d = c >> 2, g = c & 3;
    float w = 0.f;
    if (d < 100) {
        if (k < 100) {
            if (g == 0)      w = Wih[d * 100 + k];
            else if (g == 1) w = Wih[(100 + d) * 100 + k];
            else if (g == 2) w = Wih[(200 + d) * 100 + k];
        } else if (k >= 112 && k < 212) {
            int kk = k - 112;
            if (g == 0)      w = Whh[d * 100 + kk];
            else if (g == 1) w = Whh[(100 + d) * 100 + kk];
            else if (g == 3) w = Whh[(200 + d) * 100 + kk];
        }
    }
    uint32 h, m, l; split3(w, h, m, l);
    W0[gid] = (ushort_t)h; W1[gid] = (ushort_t)m; W2[gid] = (ushort_t)l;
    if (k == 0) {
        float b = 0.f;
        if (d < 100) {
            if (g == 0)      b = bih[d] + bhh[d];
            else if (g == 1) b = bih[100 + d] + bhh[100 + d];
            else if (g == 2) b = bih[200 + d];
            else             b = bhh[200 + d];
        }
        bg[c] = b;
    }
}

// msg MLP: W1t[c<64][k<128] (c=hidden col, k=h dim), W2t[c<112][k<64]
__global__ void prep_msg_w(const float* __restrict__ W1, const float* __restrict__ b1,
                           const float* __restrict__ W2, const float* __restrict__ b2,
                           ushort_t* __restrict__ A0, ushort_t* __restrict__ A1,
                           ushort_t* __restrict__ A2, float* __restrict__ b1p,
                           ushort_t* __restrict__ B0, ushort_t* __restrict__ B1,
                           ushort_t* __restrict__ B2, float* __restrict__ b2p) {
    int gid = blockIdx.x * 256 + threadIdx.x;
    if (gid < 8192) {
        int c = gid >> 7, k = gid & 127;
        float w = (c < 50 && k < 100) ? W1[k * 50 + c] : 0.f;
        uint32 h, m, l; split3(w, h, m, l);
        A0[gid] = (ushort_t)h; A1[gid] = (ushort_t)m; A2[gid] = (ushort_t)l;
        if (k == 0) b1p[c] = (c < 50) ? b1[c] : 0.f;
    } else if (gid < 8192 + 7168) {
        int t = gid - 8192;
        int c = t >> 6, k = t & 63;
        float w = (c < 100 && k < 50) ? W2[k * 100 + c] : 0.f;
        uint32 h, m, l; split3(w, h, m, l);
        B0[t] = (ushort_t)h; B1[t] = (ushort_t)m; B2[t] = (ushort_t)l;
        if (k == 0) b2p[c] = (c < 100) ? b2[c] : 0.f;
    }
}

// ---------------------------------------------------------------- init h
// h0 = feat @ init_W + b, split to limbs at k in [112,212) of the limb planes.
__global__ void init_h_kernel(const float* __restrict__ feat, const float* __restrict__ W,
                              const float* __restrict__ b,
                              ushort_t* __restrict__ L0, ushort_t* __restrict__ L1,
                              ushort_t* __restrict__ L2) {
    int gid = blockIdx.x * 256 + threadIdx.x;   // N*100
    if (gid >= Nn * 100) return;
    int n = gid / 100, d = gid - n * 100;
    float acc = b[d];
#pragma unroll
    for (int k = 0; k < 4; k++) acc += feat[n * 4 + k] * W[k * 100 + d];
    uint32 h, m, l; split3(acc, h, m, l);
    size_t a = (size_t)n * LROW + 112 + d;
    L0[a] = (ushort_t)h; L1[a] = (ushort_t)m; L2[a] = (ushort_t)l;
}

// ---------------------------------------------------------------- msg MLP (MFMA)
// fm = relu(h @ W1 + b1) @ W2 + b2 ; computed transposed: D[c][n].
__global__ __launch_bounds__(256, 2) void msg_mfma(
    const ushort_t* __restrict__ L0, const ushort_t* __restrict__ L1,
    const ushort_t* __restrict__ L2,
    const ushort_t* __restrict__ A0, const ushort_t* __restrict__ A1,
    const ushort_t* __restrict__ A2, const float* __restrict__ b1p,
    const ushort_t* __restrict__ B0, const ushort_t* __restrict__ B1,
    const ushort_t* __restrict__ B2, const float* __restrict__ b2p,
    float* __restrict__ fm) {
    __shared__ ushort_t C1[3][64][72];
    const int tid = threadIdx.x;
    const int u = tid >> 6;          // wave = node tile
    const int lane = tid & 63;
    const int m = lane & 15, q = lane >> 4;
    const int n0 = blockIdx.x * 64;
    const int n = n0 + u * 16 + m;

    f32x4 z = {0.f, 0.f, 0.f, 0.f};
    f32x4 a1[4] = {z, z, z, z};

    const size_t hbase = (size_t)n * LROW + 112;
    for (int kc = 0; kc < 4; kc++) {
        int kb = kc * 32 + q * 8;
        // k in [kb,kb+8): real h for k<100, zeros for pad; kc==3 upper q
        // over-reads into next row's msg area / tail pad — finite, and
        // A-weights are zero for k>=100.
        short8 f0 = *(const short8*)(L0 + hbase + kb);
        short8 f1 = *(const short8*)(L1 + hbase + kb);
        short8 f2 = *(const short8*)(L2 + hbase + kb);
#pragma unroll
        for (int t = 0; t < 4; t++) {
            int off = (t * 16 + m) * 128 + kc * 32 + q * 8;
            short8 w0 = *(const short8*)(A0 + off);
            short8 w1 = *(const short8*)(A1 + off);
            short8 w2 = *(const short8*)(A2 + off);
            a1[t] = mfma16(w0, f0, a1[t]);
            a1[t] = mfma16(w0, f1, a1[t]);
            a1[t] = mfma16(w1, f0, a1[t]);
            a1[t] = mfma16(w0, f2, a1[t]);
            a1[t] = mfma16(w2, f0, a1[t]);
            a1[t] = mfma16(w1, f1, a1[t]);
        }
    }
    // epilogue 1: relu + split -> LDS
#pragma unroll
    for (int t = 0; t < 4; t++) {
        int c0 = t * 16 + 4 * q;
        float4 bb = *(const float4*)&b1p[c0];
        float v0 = fmaxf(a1[t][0] + bb.x, 0.f);
        float v1 = fmaxf(a1[t][1] + bb.y, 0.f);
        float v2 = fmaxf(a1[t][2] + bb.z, 0.f);
        float v3 = fmaxf(a1[t][3] + bb.w, 0.f);
        uint32 h0, m0, l0, h1, m1, l1, h2, m2, l2, h3, m3, l3;
        split3(v0, h0, m0, l0); split3(v1, h1, m1, l1);
        split3(v2, h2, m2, l2); split3(v3, h3, m3, l3);
        int nl = u * 16 + m;
        *(uint2*)&C1[0][nl][c0] = make_uint2(h0 | (h1 << 16), h2 | (h3 << 16));
        *(uint2*)&C1[1][nl][c0] = make_uint2(m0 | (m1 << 16), m2 | (m3 << 16));
        *(uint2*)&C1[2][nl][c0] = make_uint2(l0 | (l1 << 16), l2 | (l3 << 16));
    }
    __syncthreads();

    f32x4 a2[7] = {z, z, z, z, z, z, z};
    for (int kc = 0; kc < 2; kc++) {
        int nl = u * 16 + m;
        short8 c0f = *(const short8*)&C1[0][nl][kc * 32 + q * 8];
        short8 c1f = *(const short8*)&C1[1][nl][kc * 32 + q * 8];
        short8 c2f = *(const short8*)&C1[2][nl][kc * 32 + q * 8];
#pragma unroll
        for (int t = 0; t < 7; t++) {
            int off = (t * 16 + m) * 64 + kc * 32 + q * 8;
            short8 w0 = *(const short8*)(B0 + off);
            short8 w1 = *(const short8*)(B1 + off);
            short8 w2 = *(const short8*)(B2 + off);
            a2[t] = mfma16(w0, c0f, a2[t]);
            a2[t] = mfma16(w0, c1f, a2[t]);
            a2[t] = mfma16(w1, c0f, a2[t]);
            a2[t] = mfma16(w0, c2f, a2[t]);
            a2[t] = mfma16(w2, c0f, a2[t]);
            a2[t] = mfma16(w1, c1f, a2[t]);
        }
    }
#pragma unroll
    for (int t = 0; t < 7; t++) {
        int c0 = t * 16 + 4 * q;
        if (c0 < 100) {
            float4 bb = *(const float4*)&b2p[c0];
            float4 o;
            o.x = a2[t][0] + bb.x; o.y = a2[t][1] + bb.y;
            o.z = a2[t][2] + bb.z; o.w = a2[t][3] + bb.w;
            *(float4*)&fm[(size_t)n * 100 + c0] = o;
        }
    }
}

// ---------------------------------------------------------------- gather (CSR)
// Sums messages over incoming edges; stores the 3-limb split directly to the
// limb planes at k in [0,100) (gru's x = msg part). High occupancy hides the
// random fm-row latency.
__global__ void gather4(const float* __restrict__ fm, const int* __restrict__ ptr,
                        const int* __restrict__ idx,
                        ushort_t* __restrict__ L0, ushort_t* __restrict__ L1,
                        ushort_t* __restrict__ L2) {
    int gid = blockIdx.x * 256 + threadIdx.x;   // N*25
    int n = gid / 25, qq = (gid - n * 25) * 4;
    int s = (n == 0) ? 0 : ptr[n - 1];
    int e = ptr[n];
    float4 acc = {0.f, 0.f, 0.f, 0.f};
    for (int i = s; i < e; i++) {
        float4 v = *(const float4*)&fm[(size_t)idx[i] * 100 + qq];
        acc.x += v.x; acc.y += v.y; acc.z += v.z; acc.w += v.w;
    }
    uint32 h0, m0, l0, h1, m1, l1, h2, m2, l2, h3, m3, l3;
    split3(acc.x, h0, m0, l0); split3(acc.y, h1, m1, l1);
    split3(acc.z, h2, m2, l2); split3(acc.w, h3, m3, l3);
    size_t a = (size_t)n * LROW + qq;
    *(uint2*)&L0[a] = make_uint2(h0 | (h1 << 16), h2 | (h3 << 16));
    *(uint2*)&L1[a] = make_uint2(m0 | (m1 << 16), m2 | (m3 << 16));
    *(uint2*)&L2[a] = make_uint2(l0 | (l1 << 16), l2 | (l3 << 16));
}

// ---------------------------------------------------------------- GRU v12
// THE CONSTRAINT (diagnosed r7): v5..v11 all ran 240 regs/wave (128 VGPR +
// 112 acc-AGPR) -> 2 waves/SIMD occupancy cliff -> MFMA pipe ~38% fed,
// regardless of staging structure. v12 attacks the register budget instead:
// 32 rows/block (grid 4096), 256 thr, 4 col-waves, acc[7][2] = 56 AGPR,
// single-buffered w[7] = 28 VGPR, direct global f limb loads (24 VGPR).
// Target total <= 128 regs (__launch_bounds__(256,4)) -> 4 waves/SIMD,
// 4 independent blocks/CU: TLP covers all load stalls, no LDS staging,
// no barriers in the K-loop. Epilogue = v8's vectorized LDS transpose.
__global__ __launch_bounds__(256, 4) void gru_mfma(
    ushort_t* __restrict__ L0, ushort_t* __restrict__ L1,
    ushort_t* __restrict__ L2,
    const ushort_t* __restrict__ W0, const ushort_t* __restrict__ W1,
    const ushort_t* __restrict__ W2, const float* __restrict__ bg) {
    __shared__ float sh[32][117];   // 15.0 KB; 117 coprime 32 -> conflict-light
    const int tid = threadIdx.x;
    const int wave = tid >> 6;      // col group 0..3
    const int lane = tid & 63;
    const int m = lane & 15, q = lane >> 4;
    const int n0 = blockIdx.x * 32;

    f32x4 z = {0.f, 0.f, 0.f, 0.f};
    f32x4 acc[7][2];
#pragma unroll
    for (int t = 0; t < 7; t++) {
        acc[t][0] = z; acc[t][1] = z;
    }

    // 32-bit offsets (planes < 64 MB, weights < 256 KB) -> SGPR-base+voffset
    const uint32 abase = (uint32)(n0 + m) * LROW + q * 8;
    const uint32 wbase = (uint32)((wave * 16 + m) * LROW + q * 8);

#define GP(Fr)                                                     \
    _Pragma("unroll")                                              \
    for (int t = 0; t < 7; t++) {                                  \
        acc[t][0] = mfma16(w[t], Fr[0], acc[t][0]);                \
        acc[t][1] = mfma16(w[t], Fr[1], acc[t][1]);                \
    }

    for (int kc = 0; kc < 7; kc++) {
        const uint32 ko = kc * 32;
        short8 f0[2], f1[2], f2[2];
#pragma unroll
        for (int rf = 0; rf < 2; rf++) {
            uint32 a = abase + rf * (16 * LROW) + ko;
            f0[rf] = *(const short8*)(L0 + a);
            f1[rf] = *(const short8*)(L1 + a);
            f2[rf] = *(const short8*)(L2 + a);
        }
        short8 w[7];
#pragma unroll
        for (int t = 0; t < 7; t++)
            w[t] = *(const short8*)(W0 + wbase + (uint32)(t * 64 * LROW) + ko);
        GP(f0); GP(f1); GP(f2);                         // W0 products
#pragma unroll
        for (int t = 0; t < 7; t++)
            w[t] = *(const short8*)(W1 + wbase + (uint32)(t * 64 * LROW) + ko);
        GP(f0); GP(f1);                                 // W1 products
#pragma unroll
        for (int t = 0; t < 7; t++)
            w[t] = *(const short8*)(W2 + wbase + (uint32)(t * 64 * LROW) + ko);
        GP(f0);                                         // W2 product
    }
#undef GP

    // ---- epilogue phase A: cooperative hold reconstruction -> LDS fp32.
    // row = ix>>4, c = ix&15: 16 lanes cover one row's 13 contiguous 16B
    // chunks -> coalesced global reads.
#pragma unroll
    for (int p = 0; p < 2; p++) {
        int ix = tid + p * 256;           // 512 slots: 32 rows x 16 chunks
        int row = ix >> 4, c = ix & 15;
        if (c < 13) {                     // k [0,104); [100,104) limbs are 0
            size_t g = (size_t)(n0 + row) * LROW + 112 + c * 8;
            union { short8 s; ushort_t u[8]; } a0, a1, a2;
            a0.s = *(const short8*)(L0 + g);
            a1.s = *(const short8*)(L1 + g);
            a2.s = *(const short8*)(L2 + g);
#pragma unroll
            for (int j = 0; j < 8; j++)
                sh[row][c * 8 + j] =
                    (limb2f(a2.u[j]) + limb2f(a1.u[j])) + limb2f(a0.u[j]);
        }
    }
    __syncthreads();

    // ---- epilogue phase B: gates (each (row,d) owned by exactly one thread)
#pragma unroll
    for (int t = 0; t < 7; t++) {
        const int ct = t * 4 + wave;        // 0..27
        const int d = ct * 4 + q;           // 0..111
        if (d < 100) {
            float4 b4 = *(const float4*)&bg[ct * 16 + 4 * q];
#pragma unroll
            for (int rf = 0; rf < 2; rf++) {
                int row = rf * 16 + m;
                float hold = sh[row][d];
                float rp = acc[t][rf][0] + b4.x;
                float zp = acc[t][rf][1] + b4.y;
                float np = acc[t][rf][2] + b4.z;
                float hh = acc[t][rf][3] + b4.w;
                float rr = 1.f / (1.f + __expf(-rp));
                float zz = 1.f / (1.f + __expf(-zp));
                float nw = tanhf(np + rr * hh);
                sh[row][d] = (1.f - zz) * nw + zz * hold;
            }
        }
    }
    __syncthreads();

    // ---- epilogue phase C: split + coalesced 16B limb stores to h region
#pragma unroll
    for (int p = 0; p < 2; p++) {
        int ix = tid + p * 256;
        int row = ix >> 4, c = ix & 15;
        if (c < 13) {
            size_t g = (size_t)(n0 + row) * LROW + 112 + c * 8;
            union { short8 s; uint32 u4[4]; } o0, o1, o2;
#pragma unroll
            for (int jj = 0; jj < 4; jj++) {
                float ea = sh[row][c * 8 + 2 * jj];
                float eb = sh[row][c * 8 + 2 * jj + 1];
                uint32 ha, ma, la, hb, mb, lb;
                split3(ea, ha, ma, la);
                split3(eb, hb, mb, lb);
                o0.u4[jj] = ha | (hb << 16);
                o1.u4[jj] = ma | (mb << 16);
                o2.u4[jj] = la | (lb << 16);
            }
            *(short8*)(L0 + g) = o0.s;
            *(short8*)(L1 + g) = o1.s;
            *(short8*)(L2 + g) = o2.s;
        }
    }
}

// ---------------------------------------------------------------- classifier
__global__ __launch_bounds__(256) void classifier(
    const ushort_t* __restrict__ L0, const ushort_t* __restrict__ L1,
    const ushort_t* __restrict__ L2, const float* __restrict__ W1,
    const float* __restrict__ b1, const float* __restrict__ W2,
    const float* __restrict__ b2, float* __restrict__ out) {
    __shared__ float Wc[3128];   // [3000,3128) zero pad: k in [100,104) rows
    __shared__ float bc[30];
    __shared__ float w2[30];
    int tid = threadIdx.x;
    for (int i = tid; i < 3128; i += 256) Wc[i] = (i < 3000) ? W1[i] : 0.f;
    if (tid < 30) { bc[tid] = b1[tid]; w2[tid] = W2[tid]; }
    __syncthreads();
    int n = blockIdx.x * 256 + tid;
    float a[30];
#pragma unroll
    for (int j = 0; j < 30; j++) a[j] = bc[j];
    const size_t base = (size_t)n * LROW + 112;
    for (int k8 = 0; k8 < 13; k8++) {     // k in [0,104); [100,104) limbs are 0
        int k0 = k8 * 8;
        union { short8 s; ushort_t u[8]; } h0, h1, h2;
        h0.s = *(const short8*)(L0 + base + k0);
        h1.s = *(const short8*)(L1 + base + k0);
        h2.s = *(const short8*)(L2 + base + k0);
#pragma unroll
        for (int jj = 0; jj < 8; jj++) {
            float hv = (limb2f(h2.u[jj]) + limb2f(h1.u[jj])) + limb2f(h0.u[jj]);
#pragma unroll
            for (int j = 0; j < 30; j++) a[j] = fmaf(hv, Wc[(k0 + jj) * 30 + j], a[j]);
        }
    }
    float s = b2[0];
#pragma unroll
    for (int j = 0; j < 30; j++) s = fmaf(fmaxf(a[j], 0.f), w2[j], s);
    out[n] = s;
}

// ---------------------------------------------------------------- launch
extern "C" void kernel_launch(void* const* d_in, const int* in_sizes, int n_in,
                              void* d_out, int out_size, void* d_ws, size_t ws_size,
                              hipStream_t stream) {
    const float* feat     = (const float*)d_in[0];
    const int*   er       = (const int*)d_in[1];
    const int*   ec       = (const int*)d_in[2];
    const float* init_W   = (const float*)d_in[3];
    const float* init_b   = (const float*)d_in[4];
    const float* fmsg_W1  = (const float*)d_in[5];
    const float* fmsg_b1  = (const float*)d_in[6];
    const float* fmsg_W2  = (const float*)d_in[7];
    const float* fmsg_b2  = (const float*)d_in[8];
    const float* bmsg_W1  = (const float*)d_in[9];
    const float* bmsg_b1  = (const float*)d_in[10];
    const float* bmsg_W2  = (const float*)d_in[11];
    const float* bmsg_b2  = (const float*)d_in[12];
    const float* fgru_Wih = (const float*)d_in[13];
    const float* fgru_Whh = (const float*)d_in[14];
    const float* fgru_bih = (const float*)d_in[15];
    const float* fgru_bhh = (const float*)d_in[16];
    const float* bgru_Wih = (const float*)d_in[17];
    const float* bgru_Whh = (const float*)d_in[18];
    const float* bgru_bih = (const float*)d_in[19];
    const float* bgru_bhh = (const float*)d_in[20];
    const float* cls_W1   = (const float*)d_in[21];
    const float* cls_b1   = (const float*)d_in[22];
    const float* cls_W2   = (const float*)d_in[23];
    const float* cls_b2   = (const float*)d_in[24];
    float* out = (float*)d_out;

    // Workspace budget (256 MiB = 268.4 MB hard limit):
    //   fm           52.43 MB
    //   limb planes 176.16 MB (3 x (Nn*224+64) shorts)
    //   weights      ~1.39 MB, biases ~5 KB
    //   CSR ints     ~6.29 MB
    //   total       ~236.3 MB  OK
    float* ws = (float*)d_ws;
    size_t o = 0;
    float* fm = ws + o; o += (size_t)Nn * 100;            // [N][100] fp32

    const size_t PL = (size_t)Nn * LROW + 64;             // limb plane size (shorts)
    ushort_t* us = (ushort_t*)(ws + o);
    size_t uo = 0;
    ushort_t* L0 = us + uo; uo += PL;
    ushort_t* L1 = us + uo; uo += PL;
    ushort_t* L2 = us + uo; uo += PL;
    ushort_t* fWg0 = us + uo; uo += 448 * 224;
    ushort_t* fWg1 = us + uo; uo += 448 * 224;
    ushort_t* fWg2 = us + uo; uo += 448 * 224;
    ushort_t* bWg0 = us + uo; uo += 448 * 224;
    ushort_t* bWg1 = us + uo; uo += 448 * 224;
    ushort_t* bWg2 = us + uo; uo += 448 * 224;
    ushort_t* fA0 = us + uo; uo += 8192;
    ushort_t* fA1 = us + uo; uo += 8192;
    ushort_t* fA2 = us + uo; uo += 8192;
    ushort_t* bA0 = us + uo; uo += 8192;
    ushort_t* bA1 = us + uo; uo += 8192;
    ushort_t* bA2 = us + uo; uo += 8192;
    ushort_t* fB0 = us + uo; uo += 7168;
    ushort_t* fB1 = us + uo; uo += 7168;
    ushort_t* fB2 = us + uo; uo += 7168;
    ushort_t* bB0 = us + uo; uo += 7168;
    ushort_t* bB1 = us + uo; uo += 7168;
    ushort_t* bB2 = us + uo; uo += 7168;     // uo even
    o += uo / 2;

    float* bgf  = ws + o; o += 448;
    float* bgb  = ws + o; o += 448;
    float* b1pf = ws + o; o += 64;
    float* b1pb = ws + o; o += 64;
    float* b2pf = ws + o; o += 112;
    float* b2pb = ws + o; o += 112;

    int* iws   = (int*)(ws + o);
    int* ptr_f = iws;                       // Nn+4 (padded for int4 alignment)
    int* ptr_b = ptr_f + (Nn + 4);          // Nn+4
    int* cnt   = ptr_b + (Nn + 4);          // 2N (16B-aligned)
    int* cnt_f = cnt;
    int* cnt_b = cnt + Nn;
    int* src_f = cnt + 2 * (size_t)Nn;      // E
    int* src_b = src_f + Ee;                // E

    size_t need = o * sizeof(float) +
                  (size_t)(2 * (Nn + 4) + 2 * Nn + 2 * Ee) * sizeof(int);
    if (ws_size < need) {
        diag_kernel<<<(Nn + 255) / 256, 256, 0, stream>>>(out, (float)ws_size);
        return;
    }

    // zero limb planes once (pads [100,112) and [212,224) must stay 0; tail pad)
    {
        long n8 = (long)(3 * PL / 8);
        zero_short8<<<(int)((n8 + 255) / 256), 256, 0, stream>>>(L0, n8);
    }

    // CSR build
    zero_ints<<<(2 * Nn + 255) / 256, 256, 0, stream>>>(cnt, 2 * Nn);
    hist_kernel<<<Ee / 256, 256, 0, stream>>>(er, ec, cnt_f, cnt_b);
    scan2_kernel<<<2, 1024, 0, stream>>>(cnt_f, cnt_b, ptr_f, ptr_b, Nn);
    fill_kernel<<<Ee / 256, 256, 0, stream>>>(er, ec, ptr_f, ptr_b, src_f, src_b);

    // weight prep (split to 3 bf16 limbs)
    prep_gru_w<<<(448 * 224 + 255) / 256, 256, 0, stream>>>(
        fgru_Wih, fgru_Whh, fgru_bih, fgru_bhh, fWg0, fWg1, fWg2, bgf);
    prep_gru_w<<<(448 * 224 + 255) / 256, 256, 0, stream>>>(
        bgru_Wih, bgru_Whh, bgru_bih, bgru_bhh, bWg0, bWg1, bWg2, bgb);
    prep_msg_w<<<(15360 + 255) / 256, 256, 0, stream>>>(
        fmsg_W1, fmsg_b1, fmsg_W2, fmsg_b2, fA0, fA1, fA2, b1pf, fB0, fB1, fB2, b2pf);
    prep_msg_w<<<(15360 + 255) / 256, 256, 0, stream>>>(
        bmsg_W1, bmsg_b1, bmsg_W2, bmsg_b2, bA0, bA1, bA2, b1pb, bB0, bB1, bB2, b2pb);

    // h init (writes h limbs)
    init_h_kernel<<<(Nn * 100 + 255) / 256, 256, 0, stream>>>(
        feat, init_W, init_b, L0, L1, L2);

    const int gTile = Nn / 64;            // 2048 (msg)
    const int gGru  = Nn / 32;            // 4096 (gru, 32 rows/block)
    const int gGath = Nn * 25 / 256;      // 12800

    for (int rd = 0; rd < 20; rd++) {
        msg_mfma<<<gTile, 256, 0, stream>>>(L0, L1, L2,
            fA0, fA1, fA2, b1pf, fB0, fB1, fB2, b2pf, fm);
        gather4<<<gGath, 256, 0, stream>>>(fm, ptr_f, src_f, L0, L1, L2);
        gru_mfma<<<gGru, 256, 0, stream>>>(L0, L1, L2, fWg0, fWg1, fWg2, bgf);

        msg_mfma<<<gTile, 256, 0, stream>>>(L0, L1, L2,
            bA0, bA1, bA2, b1pb, bB0, bB1, bB2, b2pb, fm);
        gather4<<<gGath, 256, 0, stream>>>(fm, ptr_b, src_b, L0, L1, L2);
        gru_mfma<<<gGru, 256, 0, stream>>>(L0, L1, L2, bWg0, bWg1, bWg2, bgb);
    }

    classifier<<<Nn / 256, 256, 0, stream>>>(L0, L1, L2,
        cls_W1, cls_b1, cls_W2, cls_b2, out);
}

// Round 9
// 12950.061 us; speedup vs baseline: 1.1928x; 1.1928x over previous
//
#include <hip/hip_runtime.h>
#include <math.h>

#define Nn 131072
#define Ee 524288

typedef __attribute__((ext_vector_type(8))) short short8;
typedef __attribute__((ext_vector_type(4))) float f32x4;
typedef unsigned short ushort_t;
typedef unsigned int uint32;

__device__ __forceinline__ f32x4 mfma16(short8 a, short8 b, f32x4 c) {
    return __builtin_amdgcn_mfma_f32_16x16x32_bf16(a, b, c, 0, 0, 0);
}

__device__ __forceinline__ uint32 rne_bf16(float x) {
    uint32 u = __float_as_uint(x);
    return (u + 0x7FFFu + ((u >> 16) & 1u)) >> 16;
}

// fp32 -> 3 bf16 limbs (hi, mid, lo); hi+mid+lo ~= x to ~2^-27 rel.
__device__ __forceinline__ void split3(float x, uint32& h, uint32& m, uint32& l) {
    h = rne_bf16(x);
    float hf = __uint_as_float(h << 16);
    float r1 = x - hf;
    m = rne_bf16(r1);
    float mf = __uint_as_float(m << 16);
    float r2 = r1 - mf;
    l = rne_bf16(r2);
}

// ---------------------------------------------------------------- diag / zero
__global__ void diag_kernel(float* out, float val) {
    int n = blockIdx.x * 256 + threadIdx.x;
    if (n < Nn) out[n] = (n == 0) ? val : 0.f;
}
__global__ void zero_ints(int* p, int n) {
    int i = blockIdx.x * 256 + threadIdx.x;
    if (i < n) p[i] = 0;
}

// ---------------------------------------------------------------- CSR build
__global__ void hist_kernel(const int* __restrict__ er, const int* __restrict__ ec,
                            int* __restrict__ cnt_f, int* __restrict__ cnt_b) {
    int e = blockIdx.x * 256 + threadIdx.x;
    atomicAdd(&cnt_f[er[e]], 1);
    atomicAdd(&cnt_b[ec[e]], 1);
}

// two independent scans in one launch (block 0: forward, block 1: backward);
// int4-vectorized serial phases (replaces 2x196us serial scalar scans; this
// exact kernel passed in R6-R8). Writes exclusive prefix; fill advances in
// place so afterwards start(r)=(r?ptr[r-1]:0), end(r)=ptr[r].
__global__ __launch_bounds__(1024) void scan2_kernel(
    const int* __restrict__ cnt_f, const int* __restrict__ cnt_b,
    int* __restrict__ ptr_f, int* __restrict__ ptr_b, int n) {
    const int* cnt = blockIdx.x ? cnt_b : cnt_f;
    int* ptr = blockIdx.x ? ptr_b : ptr_f;
    __shared__ int sums[1024];
    int t = threadIdx.x;
    int chunk = n >> 10;                 // 128
    int base = t * chunk;
    const int4* cp = (const int4*)(cnt + base);
    int s = 0;
#pragma unroll 4
    for (int i = 0; i < 32; i++) {
        int4 v = cp[i];
        s += v.x + v.y + v.z + v.w;
    }
    sums[t] = s;
    __syncthreads();
    for (int off = 1; off < 1024; off <<= 1) {
        int v = (t >= off) ? sums[t - off] : 0;
        __syncthreads();
        sums[t] += v;
        __syncthreads();
    }
    int run = (t == 0) ? 0 : sums[t - 1];
    int4* pp = (int4*)(ptr + base);
#pragma unroll 4
    for (int i = 0; i < 32; i++) {
        int4 v = cp[i];
        int4 o;
        o.x = run; run += v.x;
        o.y = run; run += v.y;
        o.z = run; run += v.z;
        o.w = run; run += v.w;
        pp[i] = o;
    }
    if (t == 1023) ptr[n] = run;
}

// fill advances ptr in place
__global__ void fill_kernel(const int* __restrict__ er, const int* __restrict__ ec,
                            int* __restrict__ ptr_f, int* __restrict__ ptr_b,
                            int* __restrict__ src_f, int* __restrict__ src_b) {
    int e = blockIdx.x * 256 + threadIdx.x;
    int r = er[e], c = ec[e];
    int p = atomicAdd(&ptr_f[r], 1); src_f[p] = c;
    int q = atomicAdd(&ptr_b[c], 1); src_b[q] = r;
}

// ---------------------------------------------------------------- weight prep
// GRU: Wt[c=4d+g][k], c<448 (28 tiles), k<100: Wih, 100<=k<200: Whh, else 0.
__global__ void prep_gru_w(const float* __restrict__ Wih, const float* __restrict__ Whh,
                           const float* __restrict__ bih, const float* __restrict__ bhh,
                           ushort_t* __restrict__ W0, ushort_t* __restrict__ W1,
                           ushort_t* __restrict__ W2, float* __restrict__ bg) {
    int gid = blockIdx.x * 256 + threadIdx.x;
    if (gid >= 448 * 224) return;
    int c = gid / 224, k = gid - c * 224;
    int d = c >> 2, g = c & 3;
    float w = 0.f;
    if (d < 100) {
        if (k < 100) {
            if (g == 0)      w = Wih[d * 100 + k];
            else if (g == 1) w = Wih[(100 + d) * 100 + k];
            else if (g == 2) w = Wih[(200 + d) * 100 + k];
        } else if (k < 200) {
            int kk = k - 100;
            if (g == 0)      w = Whh[d * 100 + kk];
            else if (g == 1) w = Whh[(100 + d) * 100 + kk];
            else if (g == 3) w = Whh[(200 + d) * 100 + kk];
        }
    }
    uint32 h, m, l; split3(w, h, m, l);
    W0[gid] = (ushort_t)h; W1[gid] = (ushort_t)m; W2[gid] = (ushort_t)l;
    if (k == 0) {
        float b = 0.f;
        if (d < 100) {
            if (g == 0)      b = bih[d] + bhh[d];
            else if (g == 1) b = bih[100 + d] + bhh[100 + d];
            else if (g == 2) b = bih[200 + d];
            else             b = bhh[200 + d];
        }
        bg[c] = b;
    }
}

// msg MLP: W1t[c<64][k<128] (c=hidden col, k=h dim), W2t[c<112][k<64]
__global__ void prep_msg_w(const float* __restrict__ W1, const float* __restrict__ b1,
                           const float* __restrict__ W2, const float* __restrict__ b2,
                           ushort_t* __restrict__ A0, ushort_t* __restrict__ A1,
                           ushort_t* __restrict__ A2, float* __restrict__ b1p,
                           ushort_t* __restrict__ B0, ushort_t* __restrict__ B1,
                           ushort_t* __restrict__ B2, float* __restrict__ b2p) {
    int gid = blockIdx.x * 256 + threadIdx.x;
    if (gid < 8192) {
        int c = gid >> 7, k = gid & 127;
        float w = (c < 50 && k < 100) ? W1[k * 50 + c] : 0.f;
        uint32 h, m, l; split3(w, h, m, l);
        A0[gid] = (ushort_t)h; A1[gid] = (ushort_t)m; A2[gid] = (ushort_t)l;
        if (k == 0) b1p[c] = (c < 50) ? b1[c] : 0.f;
    } else if (gid < 8192 + 7168) {
        int t = gid - 8192;
        int c = t >> 6, k = t & 63;
        float w = (c < 100 && k < 50) ? W2[k * 100 + c] : 0.f;
        uint32 h, m, l; split3(w, h, m, l);
        B0[t] = (ushort_t)h; B1[t] = (ushort_t)m; B2[t] = (ushort_t)l;
        if (k == 0) b2p[c] = (c < 100) ? b2[c] : 0.f;
    }
}

// ---------------------------------------------------------------- init h
__global__ void init_h_kernel(const float* __restrict__ feat, const float* __restrict__ W,
                              const float* __restrict__ b, float* __restrict__ Act) {
    int gid = blockIdx.x * 256 + threadIdx.x;   // N*100
    int n = gid / 100, d = gid - n * 100;
    float acc = b[d];
#pragma unroll
    for (int k = 0; k < 4; k++) acc += feat[n * 4 + k] * W[k * 100 + d];
    Act[(size_t)n * 200 + 100 + d] = acc;
}

// ---------------------------------------------------------------- msg MLP (MFMA)
// fm = relu(h @ W1 + b1) @ W2 + b2 ; computed transposed: D[c][n]
__global__ __launch_bounds__(256, 2) void msg_mfma(
    const float* __restrict__ Act,
    const ushort_t* __restrict__ A0, const ushort_t* __restrict__ A1,
    const ushort_t* __restrict__ A2, const float* __restrict__ b1p,
    const ushort_t* __restrict__ B0, const ushort_t* __restrict__ B1,
    const ushort_t* __restrict__ B2, const float* __restrict__ b2p,
    float* __restrict__ fm) {
    __shared__ ushort_t C1[3][64][72];
    const int tid = threadIdx.x;
    const int u = tid >> 6;          // wave = node tile
    const int lane = tid & 63;
    const int m = lane & 15, q = lane >> 4;
    const int n0 = blockIdx.x * 64;
    const int n = n0 + u * 16 + m;

    f32x4 z = {0.f, 0.f, 0.f, 0.f};
    f32x4 a1[4] = {z, z, z, z};

    for (int kc = 0; kc < 4; kc++) {
        int kb = kc * 32 + q * 8;
        const float* src = Act + (size_t)n * 200 + 100 + kb;
        float4 v0 = *(const float4*)src;
        float4 v1 = *(const float4*)(src + 4);
        float e[8] = {v0.x, v0.y, v0.z, v0.w, v1.x, v1.y, v1.z, v1.w};
        union { short8 s; uint32 u4[4]; } f0, f1, f2;
#pragma unroll
        for (int j = 0; j < 4; j++) {
            uint32 ha, ma, la, hb, mb, lb;
            split3(e[2 * j], ha, ma, la);
            split3(e[2 * j + 1], hb, mb, lb);
            f0.u4[j] = ha | (hb << 16);
            f1.u4[j] = ma | (mb << 16);
            f2.u4[j] = la | (lb << 16);
        }
#pragma unroll
        for (int t = 0; t < 4; t++) {
            int off = (t * 16 + m) * 128 + kc * 32 + q * 8;
            short8 w0 = *(const short8*)(A0 + off);
            short8 w1 = *(const short8*)(A1 + off);
            short8 w2 = *(const short8*)(A2 + off);
            a1[t] = mfma16(w0, f0.s, a1[t]);
            a1[t] = mfma16(w0, f1.s, a1[t]);
            a1[t] = mfma16(w1, f0.s, a1[t]);
            a1[t] = mfma16(w0, f2.s, a1[t]);
            a1[t] = mfma16(w2, f0.s, a1[t]);
            a1[t] = mfma16(w1, f1.s, a1[t]);
        }
    }
    // epilogue 1: relu + split -> LDS
#pragma unroll
    for (int t = 0; t < 4; t++) {
        int c0 = t * 16 + 4 * q;
        float4 bb = *(const float4*)&b1p[c0];
        float v0 = fmaxf(a1[t][0] + bb.x, 0.f);
        float v1 = fmaxf(a1[t][1] + bb.y, 0.f);
        float v2 = fmaxf(a1[t][2] + bb.z, 0.f);
        float v3 = fmaxf(a1[t][3] + bb.w, 0.f);
        uint32 h0, m0, l0, h1, m1, l1, h2, m2, l2, h3, m3, l3;
        split3(v0, h0, m0, l0); split3(v1, h1, m1, l1);
        split3(v2, h2, m2, l2); split3(v3, h3, m3, l3);
        int nl = u * 16 + m;
        *(uint2*)&C1[0][nl][c0] = make_uint2(h0 | (h1 << 16), h2 | (h3 << 16));
        *(uint2*)&C1[1][nl][c0] = make_uint2(m0 | (m1 << 16), m2 | (m3 << 16));
        *(uint2*)&C1[2][nl][c0] = make_uint2(l0 | (l1 << 16), l2 | (l3 << 16));
    }
    __syncthreads();

    f32x4 a2[7] = {z, z, z, z, z, z, z};
    for (int kc = 0; kc < 2; kc++) {
        int nl = u * 16 + m;
        short8 c0f = *(const short8*)&C1[0][nl][kc * 32 + q * 8];
        short8 c1f = *(const short8*)&C1[1][nl][kc * 32 + q * 8];
        short8 c2f = *(const short8*)&C1[2][nl][kc * 32 + q * 8];
#pragma unroll
        for (int t = 0; t < 7; t++) {
            int off = (t * 16 + m) * 64 + kc * 32 + q * 8;
            short8 w0 = *(const short8*)(B0 + off);
            short8 w1 = *(const short8*)(B1 + off);
            short8 w2 = *(const short8*)(B2 + off);
            a2[t] = mfma16(w0, c0f, a2[t]);
            a2[t] = mfma16(w0, c1f, a2[t]);
            a2[t] = mfma16(w1, c0f, a2[t]);
            a2[t] = mfma16(w0, c2f, a2[t]);
            a2[t] = mfma16(w2, c0f, a2[t]);
            a2[t] = mfma16(w1, c1f, a2[t]);
        }
    }
#pragma unroll
    for (int t = 0; t < 7; t++) {
        int c0 = t * 16 + 4 * q;
        if (c0 < 100) {
            float4 bb = *(const float4*)&b2p[c0];
            float4 o;
            o.x = a2[t][0] + bb.x; o.y = a2[t][1] + bb.y;
            o.z = a2[t][2] + bb.z; o.w = a2[t][3] + bb.w;
            *(float4*)&fm[(size_t)n * 100 + c0] = o;
        }
    }
}

// ---------------------------------------------------------------- gather (CSR)
__global__ void gather4(const float* __restrict__ fm, const int* __restrict__ ptr,
                        const int* __restrict__ idx, float* __restrict__ Act) {
    int gid = blockIdx.x * 256 + threadIdx.x;   // N*25
    int n = gid / 25, qq = (gid - n * 25) * 4;
    int s = (n == 0) ? 0 : ptr[n - 1];
    int e = ptr[n];
    float4 acc = {0.f, 0.f, 0.f, 0.f};
    for (int i = s; i < e; i++) {
        float4 v = *(const float4*)&fm[(size_t)idx[i] * 100 + qq];
        acc.x += v.x; acc.y += v.y; acc.z += v.z; acc.w += v.w;
    }
    *(float4*)&Act[(size_t)n * 200 + qq] = acc;
}

// ---------------------------------------------------------------- GRU (MFMA) v5
// (Session-best configuration, R1: 199.6 us steady.) 64-row blocks, 256 thr,
// cooperative LDS staging of activation limb planes: all 256 threads split
// the 64x224 slab ONCE into LDS (2 stages: k[0,128), k[128,224); 3 limb
// planes, row stride 136 -> ~2-way banks). Weights stream from L2. At 38%
// MfmaUtil this is the 2-phase-HIP plateau: v8 (direct loads, 128 rows),
// v9 (gl_lds pipeline), v11 (barrier-light), v12 (2x occupancy) all landed
// 190-250 -> dur tracks MFMA count, invariant to staging/occupancy.
__global__ __launch_bounds__(256, 2) void gru_mfma(
    float* __restrict__ Act,
    const ushort_t* __restrict__ W0, const ushort_t* __restrict__ W1,
    const ushort_t* __restrict__ W2, const float* __restrict__ bg) {
    __shared__ ushort_t AL[3][64][136];   // 52.2 KB
    const int tid = threadIdx.x;
    const int wave = tid >> 6;
    const int lane = tid & 63;
    const int m = lane & 15, q = lane >> 4;
    const int n0 = blockIdx.x * 64;

    f32x4 z = {0.f, 0.f, 0.f, 0.f};
    f32x4 acc[7][4];
#pragma unroll
    for (int t = 0; t < 7; t++)
#pragma unroll
        for (int rf = 0; rf < 4; rf++) acc[t][rf] = z;

    int woff[7];
#pragma unroll
    for (int t = 0; t < 7; t++)
        woff[t] = ((t * 4 + wave) * 16 + m) * 224 + q * 8;

#define GPASS(Wreg, Fr)                                          \
    _Pragma("unroll")                                            \
    for (int t = 0; t < 7; t++) {                                \
        _Pragma("unroll")                                        \
        for (int rf = 0; rf < 4; rf++)                           \
            acc[t][rf] = mfma16(Wreg[t], Fr[rf], acc[t][rf]);    \
    }

// stage KS..KS+KW into AL (KW/4 float4 chunks per row); zero beyond k=200
#define GSTAGE(KS, KW)                                                        \
    for (int idx = tid; idx < 64 * ((KW) / 4); idx += 256) {                  \
        int row = idx / ((KW) / 4);                                           \
        int k4 = (idx - row * ((KW) / 4)) << 2;                               \
        int kg = (KS) + k4;                                                   \
        float e0 = 0.f, e1 = 0.f, e2 = 0.f, e3 = 0.f;                         \
        if (kg < 200) {                                                       \
            float4 v = *(const float4*)&Act[(size_t)(n0 + row) * 200 + kg];   \
            e0 = v.x; e1 = v.y; e2 = v.z; e3 = v.w;                           \
        }                                                                     \
        uint32 h0, m0, l0, h1, m1, l1, h2, m2, l2, h3, m3, l3;                \
        split3(e0, h0, m0, l0); split3(e1, h1, m1, l1);                       \
        split3(e2, h2, m2, l2); split3(e3, h3, m3, l3);                       \
        *(uint2*)&AL[0][row][k4] = make_uint2(h0 | (h1 << 16), h2 | (h3 << 16)); \
        *(uint2*)&AL[1][row][k4] = make_uint2(m0 | (m1 << 16), m2 | (m3 << 16)); \
        *(uint2*)&AL[2][row][k4] = make_uint2(l0 | (l1 << 16), l2 | (l3 << 16)); \
    }

// compute kc in [C0,C1): LDS fragment reads + weight stream + 6 product passes
#define GCOMPUTE(C0, C1)                                                      \
    for (int kc = (C0); kc < (C1); kc++) {                                    \
        const int kb = (kc - (C0)) * 32 + q * 8;                              \
        short8 f0[4], f1[4], f2[4];                                           \
        _Pragma("unroll")                                                     \
        for (int rf = 0; rf < 4; rf++) {                                      \
            int rl = rf * 16 + m;                                             \
            f0[rf] = *(const short8*)&AL[0][rl][kb];                          \
            f1[rf] = *(const short8*)&AL[1][rl][kb];                          \
            f2[rf] = *(const short8*)&AL[2][rl][kb];                          \
        }                                                                     \
        const int ko = kc * 32;                                               \
        short8 w[7];                                                          \
        _Pragma("unroll")                                                     \
        for (int t = 0; t < 7; t++) w[t] = *(const short8*)(W0 + woff[t] + ko); \
        GPASS(w, f0);                                                         \
        GPASS(w, f1);                                                         \
        GPASS(w, f2);                                                         \
        _Pragma("unroll")                                                     \
        for (int t = 0; t < 7; t++) w[t] = *(const short8*)(W1 + woff[t] + ko); \
        GPASS(w, f0);                                                         \
        GPASS(w, f1);                                                         \
        _Pragma("unroll")                                                     \
        for (int t = 0; t < 7; t++) w[t] = *(const short8*)(W2 + woff[t] + ko); \
        GPASS(w, f0);                                                         \
    }

    // ---- stage 0: k in [0,128)
    GSTAGE(0, 128)
    __syncthreads();
    GCOMPUTE(0, 4)
    __syncthreads();          // all waves done reading AL before overwrite
    // ---- stage 1: k in [128,224)
    GSTAGE(128, 96)
    __syncthreads();
    GCOMPUTE(4, 7)

#undef GPASS
#undef GSTAGE
#undef GCOMPUTE

    // epilogue: gates, in-place h update (all global Act reads completed
    // before the stage-1 barrier -> no extra sync needed)
#pragma unroll
    for (int t = 0; t < 7; t++) {
        const int ct = t * 4 + wave;        // 0..27
        const int d = ct * 4 + q;           // 0..111
        if (d < 100) {
            float4 b4 = *(const float4*)&bg[ct * 16 + 4 * q];
#pragma unroll
            for (int rf = 0; rf < 4; rf++) {
                int n = n0 + rf * 16 + m;
                float* hp = Act + (size_t)n * 200 + 100 + d;
                float hold = *hp;
                float rp = acc[t][rf][0] + b4.x;
                float zp = acc[t][rf][1] + b4.y;
                float np = acc[t][rf][2] + b4.z;
                float hh = acc[t][rf][3] + b4.w;
                float rr = 1.f / (1.f + __expf(-rp));
                float zz = 1.f / (1.f + __expf(-zp));
                float nw = tanhf(np + rr * hh);
                *hp = (1.f - zz) * nw + zz * hold;
            }
        }
    }
}

// ---------------------------------------------------------------- classifier
__global__ __launch_bounds__(256) void classifier(
    const float* __restrict__ Act, const float* __restrict__ W1,
    const float* __restrict__ b1, const float* __restrict__ W2,
    const float* __restrict__ b2, float* __restrict__ out) {
    __shared__ float Wc[3000];
    __shared__ float bc[30];
    __shared__ float w2[30];
    int tid = threadIdx.x;
    for (int i = tid; i < 3000; i += 256) Wc[i] = W1[i];
    if (tid < 30) { bc[tid] = b1[tid]; w2[tid] = W2[tid]; }
    __syncthreads();
    int n = blockIdx.x * 256 + tid;
    float a[30];
#pragma unroll
    for (int j = 0; j < 30; j++) a[j] = bc[j];
    for (int k = 0; k < 100; k++) {
        float hv = Act[(size_t)n * 200 + 100 + k];
#pragma unroll
        for (int j = 0; j < 30; j++) a[j] = fmaf(hv, Wc[k * 30 + j], a[j]);
    }
    float s = b2[0];
#pragma unroll
    for (int j = 0; j < 30; j++) s = fmaf(fmaxf(a[j], 0.f), w2[j], s);
    out[n] = s;
}

// ---------------------------------------------------------------- launch
extern "C" void kernel_launch(void* const* d_in, const int* in_sizes, int n_in,
                              void* d_out, int out_size, void* d_ws, size_t ws_size,
                              hipStream_t stream) {
    const float* feat     = (const float*)d_in[0];
    const int*   er       = (const int*)d_in[1];
    const int*   ec       = (const int*)d_in[2];
    const float* init_W   = (const float*)d_in[3];
    const float* init_b   = (const float*)d_in[4];
    const float* fmsg_W1  = (const float*)d_in[5];
    const float* fmsg_b1  = (const float*)d_in[6];
    const float* fmsg_W2  = (const float*)d_in[7];
    const float* fmsg_b2  = (const float*)d_in[8];
    const float* bmsg_W1  = (const float*)d_in[9];
    const float* bmsg_b1  = (const float*)d_in[10];
    const float* bmsg_W2  = (const float*)d_in[11];
    const float* bmsg_b2  = (const float*)d_in[12];
    const float* fgru_Wih = (const float*)d_in[13];
    const float* fgru_Whh = (const float*)d_in[14];
    const float* fgru_bih = (const float*)d_in[15];
    const float* fgru_bhh = (const float*)d_in[16];
    const float* bgru_Wih = (const float*)d_in[17];
    const float* bgru_Whh = (const float*)d_in[18];
    const float* bgru_bih = (const float*)d_in[19];
    const float* bgru_bhh = (const float*)d_in[20];
    const float* cls_W1   = (const float*)d_in[21];
    const float* cls_b1   = (const float*)d_in[22];
    const float* cls_W2   = (const float*)d_in[23];
    const float* cls_b2   = (const float*)d_in[24];
    float* out = (float*)d_out;

    // Workspace budget (256 MiB hard limit): Act 104.9 + fm 52.4 + weights
    // ~1.4 + CSR ~6.3 = ~165 MB  OK
    float* ws = (float*)d_ws;
    size_t o = 0;
    float* Act = ws + o; o += (size_t)Nn * 200;       // [N][200] msg|h fp32
    float* fm  = ws + o; o += (size_t)Nn * 100;       // [N][100] fp32

    ushort_t* us = (ushort_t*)(ws + o);
    size_t uo = 0;
    ushort_t* fWg0 = us + uo; uo += 448 * 224;
    ushort_t* fWg1 = us + uo; uo += 448 * 224;
    ushort_t* fWg2 = us + uo; uo += 448 * 224;
    ushort_t* bWg0 = us + uo; uo += 448 * 224;
    ushort_t* bWg1 = us + uo; uo += 448 * 224;
    ushort_t* bWg2 = us + uo; uo += 448 * 224;
    ushort_t* fA0 = us + uo; uo += 8192;
    ushort_t* fA1 = us + uo; uo += 8192;
    ushort_t* fA2 = us + uo; uo += 8192;
    ushort_t* bA0 = us + uo; uo += 8192;
    ushort_t* bA1 = us + uo; uo += 8192;
    ushort_t* bA2 = us + uo; uo += 8192;
    ushort_t* fB0 = us + uo; uo += 7168;
    ushort_t* fB1 = us + uo; uo += 7168;
    ushort_t* fB2 = us + uo; uo += 7168;
    ushort_t* bB0 = us + uo; uo += 7168;
    ushort_t* bB1 = us + uo; uo += 7168;
    ushort_t* bB2 = us + uo; uo += 7168;     // uo even
    o += uo / 2;

    float* bgf  = ws + o; o += 448;
    float* bgb  = ws + o; o += 448;
    float* b1pf = ws + o; o += 64;
    float* b1pb = ws + o; o += 64;
    float* b2pf = ws + o; o += 112;
    float* b2pb = ws + o; o += 112;

    int* iws   = (int*)(ws + o);
    int* ptr_f = iws;                       // Nn+4 (padded: keeps cnt 16B-aligned)
    int* ptr_b = ptr_f + (Nn + 4);          // Nn+4
    int* cnt   = ptr_b + (Nn + 4);          // 2N, 16B-aligned for int4 scan
    int* cnt_f = cnt;
    int* cnt_b = cnt + Nn;
    int* src_f = cnt + 2 * (size_t)Nn;      // E
    int* src_b = src_f + Ee;                // E

    size_t need = o * sizeof(float) +
                  (size_t)(2 * (Nn + 4) + 2 * Nn + 2 * Ee) * sizeof(int);
    if (ws_size < need) {
        diag_kernel<<<(Nn + 255) / 256, 256, 0, stream>>>(out, (float)ws_size);
        return;
    }

    // CSR build
    zero_ints<<<(2 * Nn + 255) / 256, 256, 0, stream>>>(cnt, 2 * Nn);
    hist_kernel<<<Ee / 256, 256, 0, stream>>>(er, ec, cnt_f, cnt_b);
    scan2_kernel<<<2, 1024, 0, stream>>>(cnt_f, cnt_b, ptr_f, ptr_b, Nn);
    fill_kernel<<<Ee / 256, 256, 0, stream>>>(er, ec, ptr_f, ptr_b, src_f, src_b);

    // weight prep (split to 3 bf16 limbs)
    prep_gru_w<<<(448 * 224 + 255) / 256, 256, 0, stream>>>(
        fgru_Wih, fgru_Whh, fgru_bih, fgru_bhh, fWg0, fWg1, fWg2, bgf);
    prep_gru_w<<<(448 * 224 + 255) / 256, 256, 0, stream>>>(
        bgru_Wih, bgru_Whh, bgru_bih, bgru_bhh, bWg0, bWg1, bWg2, bgb);
    prep_msg_w<<<(15360 + 255) / 256, 256, 0, stream>>>(
        fmsg_W1, fmsg_b1, fmsg_W2, fmsg_b2, fA0, fA1, fA2, b1pf, fB0, fB1, fB2, b2pf);
    prep_msg_w<<<(15360 + 255) / 256, 256, 0, stream>>>(
        bmsg_W1, bmsg_b1, bmsg_W2, bmsg_b2, bA0, bA1, bA2, b1pb, bB0, bB1, bB2, b2pb);

    // h init
    init_h_kernel<<<(Nn * 100) / 256, 256, 0, stream>>>(feat, init_W, init_b, Act);

    const int gTile = Nn / 64;            // 2048 (msg)
    const int gGru  = Nn / 64;            // 2048 (gru, 64 rows/block)
    const int gGath = Nn * 25 / 256;      // 12800

    for (int rd = 0; rd < 20; rd++) {
        msg_mfma<<<gTile, 256, 0, stream>>>(Act, fA0, fA1, fA2, b1pf, fB0, fB1, fB2, b2pf, fm);
        gather4<<<gGath, 256, 0, stream>>>(fm, ptr_f, src_f, Act);
        gru_mfma<<<gGru, 256, 0, stream>>>(Act, fWg0, fWg1, fWg2, bgf);

        msg_mfma<<<gTile, 256, 0, stream>>>(Act, bA0, bA1, bA2, b1pb, bB0, bB1, bB2, b2pb, fm);
        gather4<<<gGath, 256, 0, stream>>>(fm, ptr_b, src_b, Act);
        gru_mfma<<<gGru, 256, 0, stream>>>(Act, bWg0, bWg1, bWg2, bgb);
    }

    classifier<<<Nn / 256, 256, 0, stream>>>(Act, cls_W1, cls_b1, cls_W2, cls_b2, out);
}

// Round 10
// 12586.819 us; speedup vs baseline: 1.2272x; 1.0289x over previous
//
#include <hip/hip_runtime.h>
#include <math.h>

#define Nn 131072
#define Ee 524288

typedef __attribute__((ext_vector_type(8))) short short8;
typedef __attribute__((ext_vector_type(4))) float f32x4;
typedef unsigned short ushort_t;
typedef unsigned int uint32;

__device__ __forceinline__ f32x4 mfma16(short8 a, short8 b, f32x4 c) {
    return __builtin_amdgcn_mfma_f32_16x16x32_bf16(a, b, c, 0, 0, 0);
}

__device__ __forceinline__ uint32 rne_bf16(float x) {
    uint32 u = __float_as_uint(x);
    return (u + 0x7FFFu + ((u >> 16) & 1u)) >> 16;
}

// fp32 -> 3 bf16 limbs (hi, mid, lo); hi+mid+lo ~= x to ~2^-27 rel.
__device__ __forceinline__ void split3(float x, uint32& h, uint32& m, uint32& l) {
    h = rne_bf16(x);
    float hf = __uint_as_float(h << 16);
    float r1 = x - hf;
    m = rne_bf16(r1);
    float mf = __uint_as_float(m << 16);
    float r2 = r1 - mf;
    l = rne_bf16(r2);
}

// ---------------------------------------------------------------- diag / zero
__global__ void diag_kernel(float* out, float val) {
    int n = blockIdx.x * 256 + threadIdx.x;
    if (n < Nn) out[n] = (n == 0) ? val : 0.f;
}
__global__ void zero_ints(int* p, int n) {
    int i = blockIdx.x * 256 + threadIdx.x;
    if (i < n) p[i] = 0;
}

// ---------------------------------------------------------------- CSR build
__global__ void hist_kernel(const int* __restrict__ er, const int* __restrict__ ec,
                            int* __restrict__ cnt_f, int* __restrict__ cnt_b) {
    int e = blockIdx.x * 256 + threadIdx.x;
    atomicAdd(&cnt_f[er[e]], 1);
    atomicAdd(&cnt_b[ec[e]], 1);
}

// two independent scans in one launch (block 0: forward, block 1: backward);
// int4-vectorized serial phases. Writes exclusive prefix; fill advances in
// place so afterwards start(r)=(r?ptr[r-1]:0), end(r)=ptr[r].
__global__ __launch_bounds__(1024) void scan2_kernel(
    const int* __restrict__ cnt_f, const int* __restrict__ cnt_b,
    int* __restrict__ ptr_f, int* __restrict__ ptr_b, int n) {
    const int* cnt = blockIdx.x ? cnt_b : cnt_f;
    int* ptr = blockIdx.x ? ptr_b : ptr_f;
    __shared__ int sums[1024];
    int t = threadIdx.x;
    int chunk = n >> 10;                 // 128
    int base = t * chunk;
    const int4* cp = (const int4*)(cnt + base);
    int s = 0;
#pragma unroll 4
    for (int i = 0; i < 32; i++) {
        int4 v = cp[i];
        s += v.x + v.y + v.z + v.w;
    }
    sums[t] = s;
    __syncthreads();
    for (int off = 1; off < 1024; off <<= 1) {
        int v = (t >= off) ? sums[t - off] : 0;
        __syncthreads();
        sums[t] += v;
        __syncthreads();
    }
    int run = (t == 0) ? 0 : sums[t - 1];
    int4* pp = (int4*)(ptr + base);
#pragma unroll 4
    for (int i = 0; i < 32; i++) {
        int4 v = cp[i];
        int4 o;
        o.x = run; run += v.x;
        o.y = run; run += v.y;
        o.z = run; run += v.z;
        o.w = run; run += v.w;
        pp[i] = o;
    }
    if (t == 1023) ptr[n] = run;
}

// fill advances ptr in place
__global__ void fill_kernel(const int* __restrict__ er, const int* __restrict__ ec,
                            int* __restrict__ ptr_f, int* __restrict__ ptr_b,
                            int* __restrict__ src_f, int* __restrict__ src_b) {
    int e = blockIdx.x * 256 + threadIdx.x;
    int r = er[e], c = ec[e];
    int p = atomicAdd(&ptr_f[r], 1); src_f[p] = c;
    int q = atomicAdd(&ptr_b[c], 1); src_b[q] = r;
}

// ---------------------------------------------------------------- weight prep
// GRU: Wt[c=4d+g][k], c<448 (28 tiles), k<100: Wih, 100<=k<200: Whh, else 0.
// (gru_mfma reads only c<400 = the 25 real tiles; rows 400..447 stay allocated
// for layout-compatibility but are never loaded.)
__global__ void prep_gru_w(const float* __restrict__ Wih, const float* __restrict__ Whh,
                           const float* __restrict__ bih, const float* __restrict__ bhh,
                           ushort_t* __restrict__ W0, ushort_t* __restrict__ W1,
                           ushort_t* __restrict__ W2, float* __restrict__ bg) {
    int gid = blockIdx.x * 256 + threadIdx.x;
    if (gid >= 448 * 224) return;
    int c = gid / 224, k = gid - c * 224;
    int d = c >> 2, g = c & 3;
    float w = 0.f;
    if (d < 100) {
        if (k < 100) {
            if (g == 0)      w = Wih[d * 100 + k];
            else if (g == 1) w = Wih[(100 + d) * 100 + k];
            else if (g == 2) w = Wih[(200 + d) * 100 + k];
        } else if (k < 200) {
            int kk = k - 100;
            if (g == 0)      w = Whh[d * 100 + kk];
            else if (g == 1) w = Whh[(100 + d) * 100 + kk];
            else if (g == 3) w = Whh[(200 + d) * 100 + kk];
        }
    }
    uint32 h, m, l; split3(w, h, m, l);
    W0[gid] = (ushort_t)h; W1[gid] = (ushort_t)m; W2[gid] = (ushort_t)l;
    if (k == 0) {
        float b = 0.f;
        if (d < 100) {
            if (g == 0)      b = bih[d] + bhh[d];
            else if (g == 1) b = bih[100 + d] + bhh[100 + d];
            else if (g == 2) b = bih[200 + d];
            else             b = bhh[200 + d];
        }
        bg[c] = b;
    }
}

// msg MLP: W1t[c<64][k<128] (c=hidden col, k=h dim), W2t[c<112][k<64]
__global__ void prep_msg_w(const float* __restrict__ W1, const float* __restrict__ b1,
                           const float* __restrict__ W2, const float* __restrict__ b2,
                           ushort_t* __restrict__ A0, ushort_t* __restrict__ A1,
                           ushort_t* __restrict__ A2, float* __restrict__ b1p,
                           ushort_t* __restrict__ B0, ushort_t* __restrict__ B1,
                           ushort_t* __restrict__ B2, float* __restrict__ b2p) {
    int gid = blockIdx.x * 256 + threadIdx.x;
    if (gid < 8192) {
        int c = gid >> 7, k = gid & 127;
        float w = (c < 50 && k < 100) ? W1[k * 50 + c] : 0.f;
        uint32 h, m, l; split3(w, h, m, l);
        A0[gid] = (ushort_t)h; A1[gid] = (ushort_t)m; A2[gid] = (ushort_t)l;
        if (k == 0) b1p[c] = (c < 50) ? b1[c] : 0.f;
    } else if (gid < 8192 + 7168) {
        int t = gid - 8192;
        int c = t >> 6, k = t & 63;
        float w = (c < 100 && k < 50) ? W2[k * 100 + c] : 0.f;
        uint32 h, m, l; split3(w, h, m, l);
        B0[t] = (ushort_t)h; B1[t] = (ushort_t)m; B2[t] = (ushort_t)l;
        if (k == 0) b2p[c] = (c < 100) ? b2[c] : 0.f;
    }
}

// ---------------------------------------------------------------- init h
__global__ void init_h_kernel(const float* __restrict__ feat, const float* __restrict__ W,
                              const float* __restrict__ b, float* __restrict__ Act) {
    int gid = blockIdx.x * 256 + threadIdx.x;   // N*100
    int n = gid / 100, d = gid - n * 100;
    float acc = b[d];
#pragma unroll
    for (int k = 0; k < 4; k++) acc += feat[n * 4 + k] * W[k * 100 + d];
    Act[(size_t)n * 200 + 100 + d] = acc;
}

// ---------------------------------------------------------------- msg MLP (MFMA)
// fm = relu(h @ W1 + b1) @ W2 + b2 ; computed transposed: D[c][n]
__global__ __launch_bounds__(256, 2) void msg_mfma(
    const float* __restrict__ Act,
    const ushort_t* __restrict__ A0, const ushort_t* __restrict__ A1,
    const ushort_t* __restrict__ A2, const float* __restrict__ b1p,
    const ushort_t* __restrict__ B0, const ushort_t* __restrict__ B1,
    const ushort_t* __restrict__ B2, const float* __restrict__ b2p,
    float* __restrict__ fm) {
    __shared__ ushort_t C1[3][64][72];
    const int tid = threadIdx.x;
    const int u = tid >> 6;          // wave = node tile
    const int lane = tid & 63;
    const int m = lane & 15, q = lane >> 4;
    const int n0 = blockIdx.x * 64;
    const int n = n0 + u * 16 + m;

    f32x4 z = {0.f, 0.f, 0.f, 0.f};
    f32x4 a1[4] = {z, z, z, z};

    for (int kc = 0; kc < 4; kc++) {
        int kb = kc * 32 + q * 8;
        const float* src = Act + (size_t)n * 200 + 100 + kb;
        float4 v0 = *(const float4*)src;
        float4 v1 = *(const float4*)(src + 4);
        float e[8] = {v0.x, v0.y, v0.z, v0.w, v1.x, v1.y, v1.z, v1.w};
        union { short8 s; uint32 u4[4]; } f0, f1, f2;
#pragma unroll
        for (int j = 0; j < 4; j++) {
            uint32 ha, ma, la, hb, mb, lb;
            split3(e[2 * j], ha, ma, la);
            split3(e[2 * j + 1], hb, mb, lb);
            f0.u4[j] = ha | (hb << 16);
            f1.u4[j] = ma | (mb << 16);
            f2.u4[j] = la | (lb << 16);
        }
#pragma unroll
        for (int t = 0; t < 4; t++) {
            int off = (t * 16 + m) * 128 + kc * 32 + q * 8;
            short8 w0 = *(const short8*)(A0 + off);
            short8 w1 = *(const short8*)(A1 + off);
            short8 w2 = *(const short8*)(A2 + off);
            a1[t] = mfma16(w0, f0.s, a1[t]);
            a1[t] = mfma16(w0, f1.s, a1[t]);
            a1[t] = mfma16(w1, f0.s, a1[t]);
            a1[t] = mfma16(w0, f2.s, a1[t]);
            a1[t] = mfma16(w2, f0.s, a1[t]);
            a1[t] = mfma16(w1, f1.s, a1[t]);
        }
    }
    // epilogue 1: relu + split -> LDS
#pragma unroll
    for (int t = 0; t < 4; t++) {
        int c0 = t * 16 + 4 * q;
        float4 bb = *(const float4*)&b1p[c0];
        float v0 = fmaxf(a1[t][0] + bb.x, 0.f);
        float v1 = fmaxf(a1[t][1] + bb.y, 0.f);
        float v2 = fmaxf(a1[t][2] + bb.z, 0.f);
        float v3 = fmaxf(a1[t][3] + bb.w, 0.f);
        uint32 h0, m0, l0, h1, m1, l1, h2, m2, l2, h3, m3, l3;
        split3(v0, h0, m0, l0); split3(v1, h1, m1, l1);
        split3(v2, h2, m2, l2); split3(v3, h3, m3, l3);
        int nl = u * 16 + m;
        *(uint2*)&C1[0][nl][c0] = make_uint2(h0 | (h1 << 16), h2 | (h3 << 16));
        *(uint2*)&C1[1][nl][c0] = make_uint2(m0 | (m1 << 16), m2 | (m3 << 16));
        *(uint2*)&C1[2][nl][c0] = make_uint2(l0 | (l1 << 16), l2 | (l3 << 16));
    }
    __syncthreads();

    f32x4 a2[7] = {z, z, z, z, z, z, z};
    for (int kc = 0; kc < 2; kc++) {
        int nl = u * 16 + m;
        short8 c0f = *(const short8*)&C1[0][nl][kc * 32 + q * 8];
        short8 c1f = *(const short8*)&C1[1][nl][kc * 32 + q * 8];
        short8 c2f = *(const short8*)&C1[2][nl][kc * 32 + q * 8];
#pragma unroll
        for (int t = 0; t < 7; t++) {
            int off = (t * 16 + m) * 64 + kc * 32 + q * 8;
            short8 w0 = *(const short8*)(B0 + off);
            short8 w1 = *(const short8*)(B1 + off);
            short8 w2 = *(const short8*)(B2 + off);
            a2[t] = mfma16(w0, c0f, a2[t]);
            a2[t] = mfma16(w0, c1f, a2[t]);
            a2[t] = mfma16(w1, c0f, a2[t]);
            a2[t] = mfma16(w0, c2f, a2[t]);
            a2[t] = mfma16(w2, c0f, a2[t]);
            a2[t] = mfma16(w1, c1f, a2[t]);
        }
    }
#pragma unroll
    for (int t = 0; t < 7; t++) {
        int c0 = t * 16 + 4 * q;
        if (c0 < 100) {
            float4 bb = *(const float4*)&b2p[c0];
            float4 o;
            o.x = a2[t][0] + bb.x; o.y = a2[t][1] + bb.y;
            o.z = a2[t][2] + bb.z; o.w = a2[t][3] + bb.w;
            *(float4*)&fm[(size_t)n * 100 + c0] = o;
        }
    }
}

// ---------------------------------------------------------------- gather (CSR)
// 2x unrolled with ORDER-PRESERVING accumulation (acc += v0; acc += v1) so
// the summation order — and hence absmax vs the jax reference — is unchanged;
// two fm-row loads stay in flight per iteration (latency-bound kernel).
__global__ void gather4(const float* __restrict__ fm, const int* __restrict__ ptr,
                        const int* __restrict__ idx, float* __restrict__ Act) {
    int gid = blockIdx.x * 256 + threadIdx.x;   // N*25
    int n = gid / 25, qq = (gid - n * 25) * 4;
    int s = (n == 0) ? 0 : ptr[n - 1];
    int e = ptr[n];
    float4 acc = {0.f, 0.f, 0.f, 0.f};
    int i = s;
    for (; i + 1 < e; i += 2) {
        int i0 = idx[i], i1 = idx[i + 1];
        float4 v0 = *(const float4*)&fm[(size_t)i0 * 100 + qq];
        float4 v1 = *(const float4*)&fm[(size_t)i1 * 100 + qq];
        acc.x += v0.x; acc.y += v0.y; acc.z += v0.z; acc.w += v0.w;
        acc.x += v1.x; acc.y += v1.y; acc.z += v1.z; acc.w += v1.w;
    }
    if (i < e) {
        float4 v = *(const float4*)&fm[(size_t)idx[i] * 100 + qq];
        acc.x += v.x; acc.y += v.y; acc.z += v.z; acc.w += v.w;
    }
    *(float4*)&Act[(size_t)n * 200 + qq] = acc;
}

// ---------------------------------------------------------------- GRU (MFMA) v13
// v5 structure (session best) with the 10.7% column-padding waste removed.
// Old: 28 col-tiles (448 cols), tiles 25-27 computed then discarded by the
// d<100 epilogue guard. New: balanced 25-tile decomposition — each wave does
// 6 full tiles (ct = t*4+wave, t<6, 4 row-frags each) PLUS one row-frag
// (rf = wave) of the shared tile 24 (cols 384..400). Per-wave MFMA
// 1176 -> 1050 (-10.7%), perfectly balanced, arithmetic per surviving output
// bit-identical to v5 (same products, same order). dur has tracked per-wave
// MFMA count across v5/v8/v9/v11 -> predict ~175 us.
__global__ __launch_bounds__(256, 2) void gru_mfma(
    float* __restrict__ Act,
    const ushort_t* __restrict__ W0, const ushort_t* __restrict__ W1,
    const ushort_t* __restrict__ W2, const float* __restrict__ bg) {
    __shared__ ushort_t AL[3][64][136];   // 52.2 KB
    const int tid = threadIdx.x;
    const int wave = tid >> 6;
    const int lane = tid & 63;
    const int m = lane & 15, q = lane >> 4;
    const int n0 = blockIdx.x * 64;

    f32x4 z = {0.f, 0.f, 0.f, 0.f};
    f32x4 acc[6][4];
    f32x4 accX = z;                       // tile 24, row-frag rf=wave
#pragma unroll
    for (int t = 0; t < 6; t++)
#pragma unroll
        for (int rf = 0; rf < 4; rf++) acc[t][rf] = z;

    int woff[6];
#pragma unroll
    for (int t = 0; t < 6; t++)
        woff[t] = ((t * 4 + wave) * 16 + m) * 224 + q * 8;
    const int woffX = (384 + m) * 224 + q * 8;   // tile 24 (cols 384..400)

#define GPASS(Wreg, Fr)                                          \
    _Pragma("unroll")                                            \
    for (int t = 0; t < 6; t++) {                                \
        _Pragma("unroll")                                        \
        for (int rf = 0; rf < 4; rf++)                           \
            acc[t][rf] = mfma16(Wreg[t], Fr[rf], acc[t][rf]);    \
    }

// stage KS..KS+KW into AL (KW/4 float4 chunks per row); zero beyond k=200
#define GSTAGE(KS, KW)                                                        \
    for (int idx = tid; idx < 64 * ((KW) / 4); idx += 256) {                  \
        int row = idx / ((KW) / 4);                                           \
        int k4 = (idx - row * ((KW) / 4)) << 2;                               \
        int kg = (KS) + k4;                                                   \
        float e0 = 0.f, e1 = 0.f, e2 = 0.f, e3 = 0.f;                         \
        if (kg < 200) {                                                       \
            float4 v = *(const float4*)&Act[(size_t)(n0 + row) * 200 + kg];   \
            e0 = v.x; e1 = v.y; e2 = v.z; e3 = v.w;                           \
        }                                                                     \
        uint32 h0, m0, l0, h1, m1, l1, h2, m2, l2, h3, m3, l3;                \
        split3(e0, h0, m0, l0); split3(e1, h1, m1, l1);                       \
        split3(e2, h2, m2, l2); split3(e3, h3, m3, l3);                       \
        *(uint2*)&AL[0][row][k4] = make_uint2(h0 | (h1 << 16), h2 | (h3 << 16)); \
        *(uint2*)&AL[1][row][k4] = make_uint2(m0 | (m1 << 16), m2 | (m3 << 16)); \
        *(uint2*)&AL[2][row][k4] = make_uint2(l0 | (l1 << 16), l2 | (l3 << 16)); \
    }

// compute kc in [C0,C1): LDS fragment reads + weight stream + 6 product passes
// (6 full tiles + shared tile 24's rf=wave fragment, fx*, per pass)
#define GCOMPUTE(C0, C1)                                                      \
    for (int kc = (C0); kc < (C1); kc++) {                                    \
        const int kb = (kc - (C0)) * 32 + q * 8;                              \
        short8 f0[4], f1[4], f2[4];                                           \
        _Pragma("unroll")                                                     \
        for (int rf = 0; rf < 4; rf++) {                                      \
            int rl = rf * 16 + m;                                             \
            f0[rf] = *(const short8*)&AL[0][rl][kb];                          \
            f1[rf] = *(const short8*)&AL[1][rl][kb];                          \
            f2[rf] = *(const short8*)&AL[2][rl][kb];                          \
        }                                                                     \
        const int rx = wave * 16 + m;                                         \
        short8 fx0 = *(const short8*)&AL[0][rx][kb];                          \
        short8 fx1 = *(const short8*)&AL[1][rx][kb];                          \
        short8 fx2 = *(const short8*)&AL[2][rx][kb];                          \
        const int ko = kc * 32;                                               \
        short8 w[6], wx;                                                      \
        _Pragma("unroll")                                                     \
        for (int t = 0; t < 6; t++) w[t] = *(const short8*)(W0 + woff[t] + ko); \
        wx = *(const short8*)(W0 + woffX + ko);                               \
        GPASS(w, f0); accX = mfma16(wx, fx0, accX);                           \
        GPASS(w, f1); accX = mfma16(wx, fx1, accX);                           \
        GPASS(w, f2); accX = mfma16(wx, fx2, accX);                           \
        _Pragma("unroll")                                                     \
        for (int t = 0; t < 6; t++) w[t] = *(const short8*)(W1 + woff[t] + ko); \
        wx = *(const short8*)(W1 + woffX + ko);                               \
        GPASS(w, f0); accX = mfma16(wx, fx0, accX);                           \
        GPASS(w, f1); accX = mfma16(wx, fx1, accX);                           \
        _Pragma("unroll")                                                     \
        for (int t = 0; t < 6; t++) w[t] = *(const short8*)(W2 + woff[t] + ko); \
        wx = *(const short8*)(W2 + woffX + ko);                               \
        GPASS(w, f0); accX = mfma16(wx, fx0, accX);                           \
    }

    // ---- stage 0: k in [0,128)
    GSTAGE(0, 128)
    __syncthreads();
    GCOMPUTE(0, 4)
    __syncthreads();          // all waves done reading AL before overwrite
    // ---- stage 1: k in [128,224)
    GSTAGE(128, 96)
    __syncthreads();
    GCOMPUTE(4, 7)

#undef GPASS
#undef GSTAGE
#undef GCOMPUTE

    // epilogue: gates, in-place h update (all global Act reads completed
    // before the stage-1 barrier -> no extra sync needed)
#pragma unroll
    for (int t = 0; t < 6; t++) {
        const int ct = t * 4 + wave;        // 0..23
        const int d = ct * 4 + q;           // 0..95 (< 100 always)
        float4 b4 = *(const float4*)&bg[ct * 16 + 4 * q];
#pragma unroll
        for (int rf = 0; rf < 4; rf++) {
            int n = n0 + rf * 16 + m;
            float* hp = Act + (size_t)n * 200 + 100 + d;
            float hold = *hp;
            float rp = acc[t][rf][0] + b4.x;
            float zp = acc[t][rf][1] + b4.y;
            float np = acc[t][rf][2] + b4.z;
            float hh = acc[t][rf][3] + b4.w;
            float rr = 1.f / (1.f + __expf(-rp));
            float zz = 1.f / (1.f + __expf(-zp));
            float nw = tanhf(np + rr * hh);
            *hp = (1.f - zz) * nw + zz * hold;
        }
    }
    {   // shared tile 24: d = 96..99, row-frag rf = wave
        const int d = 96 + q;
        float4 b4 = *(const float4*)&bg[384 + 4 * q];
        int n = n0 + wave * 16 + m;
        float* hp = Act + (size_t)n * 200 + 100 + d;
        float hold = *hp;
        float rp = accX[0] + b4.x;
        float zp = accX[1] + b4.y;
        float np = accX[2] + b4.z;
        float hh = accX[3] + b4.w;
        float rr = 1.f / (1.f + __expf(-rp));
        float zz = 1.f / (1.f + __expf(-zp));
        float nw = tanhf(np + rr * hh);
        *hp = (1.f - zz) * nw + zz * hold;
    }
}

// ---------------------------------------------------------------- classifier
__global__ __launch_bounds__(256) void classifier(
    const float* __restrict__ Act, const float* __restrict__ W1,
    const float* __restrict__ b1, const float* __restrict__ W2,
    const float* __restrict__ b2, float* __restrict__ out) {
    __shared__ float Wc[3000];
    __shared__ float bc[30];
    __shared__ float w2[30];
    int tid = threadIdx.x;
    for (int i = tid; i < 3000; i += 256) Wc[i] = W1[i];
    if (tid < 30) { bc[tid] = b1[tid]; w2[tid] = W2[tid]; }
    __syncthreads();
    int n = blockIdx.x * 256 + tid;
    float a[30];
#pragma unroll
    for (int j = 0; j < 30; j++) a[j] = bc[j];
    for (int k = 0; k < 100; k++) {
        float hv = Act[(size_t)n * 200 + 100 + k];
#pragma unroll
        for (int j = 0; j < 30; j++) a[j] = fmaf(hv, Wc[k * 30 + j], a[j]);
    }
    float s = b2[0];
#pragma unroll
    for (int j = 0; j < 30; j++) s = fmaf(fmaxf(a[j], 0.f), w2[j], s);
    out[n] = s;
}

// ---------------------------------------------------------------- launch
extern "C" void kernel_launch(void* const* d_in, const int* in_sizes, int n_in,
                              void* d_out, int out_size, void* d_ws, size_t ws_size,
                              hipStream_t stream) {
    const float* feat     = (const float*)d_in[0];
    const int*   er       = (const int*)d_in[1];
    const int*   ec       = (const int*)d_in[2];
    const float* init_W   = (const float*)d_in[3];
    const float* init_b   = (const float*)d_in[4];
    const float* fmsg_W1  = (const float*)d_in[5];
    const float* fmsg_b1  = (const float*)d_in[6];
    const float* fmsg_W2  = (const float*)d_in[7];
    const float* fmsg_b2  = (const float*)d_in[8];
    const float* bmsg_W1  = (const float*)d_in[9];
    const float* bmsg_b1  = (const float*)d_in[10];
    const float* bmsg_W2  = (const float*)d_in[11];
    const float* bmsg_b2  = (const float*)d_in[12];
    const float* fgru_Wih = (const float*)d_in[13];
    const float* fgru_Whh = (const float*)d_in[14];
    const float* fgru_bih = (const float*)d_in[15];
    const float* fgru_bhh = (const float*)d_in[16];
    const float* bgru_Wih = (const float*)d_in[17];
    const float* bgru_Whh = (const float*)d_in[18];
    const float* bgru_bih = (const float*)d_in[19];
    const float* bgru_bhh = (const float*)d_in[20];
    const float* cls_W1   = (const float*)d_in[21];
    const float* cls_b1   = (const float*)d_in[22];
    const float* cls_W2   = (const float*)d_in[23];
    const float* cls_b2   = (const float*)d_in[24];
    float* out = (float*)d_out;

    // Workspace budget (256 MiB hard limit): Act 104.9 + fm 52.4 + weights
    // ~1.4 + CSR ~6.3 = ~165 MB  OK
    float* ws = (float*)d_ws;
    size_t o = 0;
    float* Act = ws + o; o += (size_t)Nn * 200;       // [N][200] msg|h fp32
    float* fm  = ws + o; o += (size_t)Nn * 100;       // [N][100] fp32

    ushort_t* us = (ushort_t*)(ws + o);
    size_t uo = 0;
    ushort_t* fWg0 = us + uo; uo += 448 * 224;
    ushort_t* fWg1 = us + uo; uo += 448 * 224;
    ushort_t* fWg2 = us + uo; uo += 448 * 224;
    ushort_t* bWg0 = us + uo; uo += 448 * 224;
    ushort_t* bWg1 = us + uo; uo += 448 * 224;
    ushort_t* bWg2 = us + uo; uo += 448 * 224;
    ushort_t* fA0 = us + uo; uo += 8192;
    ushort_t* fA1 = us + uo; uo += 8192;
    ushort_t* fA2 = us + uo; uo += 8192;
    ushort_t* bA0 = us + uo; uo += 8192;
    ushort_t* bA1 = us + uo; uo += 8192;
    ushort_t* bA2 = us + uo; uo += 8192;
    ushort_t* fB0 = us + uo; uo += 7168;
    ushort_t* fB1 = us + uo; uo += 7168;
    ushort_t* fB2 = us + uo; uo += 7168;
    ushort_t* bB0 = us + uo; uo += 7168;
    ushort_t* bB1 = us + uo; uo += 7168;
    ushort_t* bB2 = us + uo; uo += 7168;     // uo even
    o += uo / 2;

    float* bgf  = ws + o; o += 448;
    float* bgb  = ws + o; o += 448;
    float* b1pf = ws + o; o += 64;
    float* b1pb = ws + o; o += 64;
    float* b2pf = ws + o; o += 112;
    float* b2pb = ws + o; o += 112;

    int* iws   = (int*)(ws + o);
    int* ptr_f = iws;                       // Nn+4 (padded: keeps cnt 16B-aligned)
    int* ptr_b = ptr_f + (Nn + 4);          // Nn+4
    int* cnt   = ptr_b + (Nn + 4);          // 2N, 16B-aligned for int4 scan
    int* cnt_f = cnt;
    int* cnt_b = cnt + Nn;
    int* src_f = cnt + 2 * (size_t)Nn;      // E
    int* src_b = src_f + Ee;                // E

    size_t need = o * sizeof(float) +
                  (size_t)(2 * (Nn + 4) + 2 * Nn + 2 * Ee) * sizeof(int);
    if (ws_size < need) {
        diag_kernel<<<(Nn + 255) / 256, 256, 0, stream>>>(out, (float)ws_size);
        return;
    }

    // CSR build
    zero_ints<<<(2 * Nn + 255) / 256, 256, 0, stream>>>(cnt, 2 * Nn);
    hist_kernel<<<Ee / 256, 256, 0, stream>>>(er, ec, cnt_f, cnt_b);
    scan2_kernel<<<2, 1024, 0, stream>>>(cnt_f, cnt_b, ptr_f, ptr_b, Nn);
    fill_kernel<<<Ee / 256, 256, 0, stream>>>(er, ec, ptr_f, ptr_b, src_f, src_b);

    // weight prep (split to 3 bf16 limbs)
    prep_gru_w<<<(448 * 224 + 255) / 256, 256, 0, stream>>>(
        fgru_Wih, fgru_Whh, fgru_bih, fgru_bhh, fWg0, fWg1, fWg2, bgf);
    prep_gru_w<<<(448 * 224 + 255) / 256, 256, 0, stream>>>(
        bgru_Wih, bgru_Whh, bgru_bih, bgru_bhh, bWg0, bWg1, bWg2, bgb);
    prep_msg_w<<<(15360 + 255) / 256, 256, 0, stream>>>(
        fmsg_W1, fmsg_b1, fmsg_W2, fmsg_b2, fA0, fA1, fA2, b1pf, fB0, fB1, fB2, b2pf);
    prep_msg_w<<<(15360 + 255) / 256, 256, 0, stream>>>(
        bmsg_W1, bmsg_b1, bmsg_W2, bmsg_b2, bA0, bA1, bA2, b1pb, bB0, bB1, bB2, b2pb);

    // h init
    init_h_kernel<<<(Nn * 100) / 256, 256, 0, stream>>>(feat, init_W, init_b, Act);

    const int gTile = Nn / 64;            // 2048 (msg)
    const int gGru  = Nn / 64;            // 2048 (gru, 64 rows/block)
    const int gGath = Nn * 25 / 256;      // 12800

    for (int rd = 0; rd < 20; rd++) {
        msg_mfma<<<gTile, 256, 0, stream>>>(Act, fA0, fA1, fA2, b1pf, fB0, fB1, fB2, b2pf, fm);
        gather4<<<gGath, 256, 0, stream>>>(fm, ptr_f, src_f, Act);
        gru_mfma<<<gGru, 256, 0, stream>>>(Act, fWg0, fWg1, fWg2, bgf);

        msg_mfma<<<gTile, 256, 0, stream>>>(Act, bA0, bA1, bA2, b1pb, bB0, bB1, bB2, b2pb, fm);
        gather4<<<gGath, 256, 0, stream>>>(fm, ptr_b, src_b, Act);
        gru_mfma<<<gGru, 256, 0, stream>>>(Act, bWg0, bWg1, bWg2, bgb);
    }

    classifier<<<Nn / 256, 256, 0, stream>>>(Act, cls_W1, cls_b1, cls_W2, cls_b2, out);
}